// Round 4
// baseline (618.508 us; speedup 1.0000x reference)
//
#include <hip/hip_runtime.h>
#include <math.h>

#define TPB 256
#define PRE_T 128           // threads AND rows per precompute tile block
#define ROWF 85             // floats per output row (C+5)

__device__ __forceinline__ float sigmoidf_(float x){
    return 1.0f / (1.0f + expf(-x));
}

__device__ __forceinline__ float bce_(float x, float t){
    // max(x,0) - x*t + log1p(exp(-|x|))
    return fmaxf(x, 0.0f) - x * t + log1pf(expf(-fabsf(x)));
}

// IoU between box a (cx,cy,w,h) and box b (cx,cy,w,h) — mirrors _pairwise_iou.
__device__ float iou_fn(float ax, float ay, float aw, float ah,
                        float bx, float by, float bw, float bh){
#pragma clang fp contract(off)
    float tlx = fmaxf(ax - aw * 0.5f, bx - bw * 0.5f);
    float tly = fmaxf(ay - ah * 0.5f, by - bh * 0.5f);
    float brx = fminf(ax + aw * 0.5f, bx + bw * 0.5f);
    float bry = fminf(ay + ah * 0.5f, by + bh * 0.5f);
    float area_a = aw * ah;
    float area_b = bw * bh;
    bool  en = (tlx < brx) && (tly < bry);
    float area_i = en ? (brx - tlx) * (bry - tly) : 0.0f;
    return area_i / (area_a + area_b - area_i + 1e-16f);
}

// Full cost(m, a). MUST be bitwise-identical between assign (selection) and
// finalize (argmin conflict resolution) — hence contract(off) and shared code.
__device__ float cost_eval(float ox, float oy, float ow, float oh,
                           float clslogit, float so, float S1,
                           float xcv, float ycv, float rad,
                           float gx, float gy, float gw, float gh,
                           bool valid, bool fgflag){
#pragma clang fp contract(off)
    if (!(valid && fgflag)) return 1e9f;   // BIG
    float raw = iou_fn(gx, gy, gw, gh, ox, oy, ow, oh);
    bool inb = (xcv > gx - 0.5f * gw) && (gx + 0.5f * gw > xcv) &&
               (ycv > gy - 0.5f * gh) && (gy + 0.5f * gh > ycv);
    bool inc = (xcv > gx - rad) && (xcv < gx + rad) &&
               (ycv > gy - rad) && (ycv < gy + rad);
    bool in_both = inb && inc;
    float pt = sqrtf(sigmoidf_(clslogit) * so);
    float logp = fmaxf(logf(pt), -100.0f);
    float l1mp = fmaxf(log1pf(-pt), -100.0f);
    float cls_cost = -(logp + S1 - l1mp);
    return cls_cost + 3.0f * (-logf(raw + 1e-8f)) + (in_both ? 0.0f : 100000.0f);
}

// ---------------- kernel 1: per-anchor precompute, LDS-tiled + transpose ----------------
// Block of PRE_T threads stages PRE_T rows (PRE_T*85 floats) into LDS via
// coalesced float4 loads, then each thread processes one row from LDS.
// Row stride 85 is odd -> 2 lanes/bank max (free on CDNA4).
__global__ __launch_bounds__(PRE_T) void precompute_kernel(
    const float* __restrict__ outputs, const float* __restrict__ xs,
    const float* __restrict__ ys, const float* __restrict__ st,
    const float* __restrict__ labels,
    float* __restrict__ S1mp, float* __restrict__ sobj, float* __restrict__ obj4,
    float* __restrict__ bce0,
    float* __restrict__ bbx, float* __restrict__ bby,
    float* __restrict__ bbw, float* __restrict__ bbh,
    unsigned char* __restrict__ fgbuf,
    int* __restrict__ amg, unsigned int* __restrict__ firstm,
    float* __restrict__ xca, float* __restrict__ yca, float* __restrict__ rada,
    float* __restrict__ clsT, int useT,
    int A, int M, int C, int B)
{
    __shared__ float lds[PRE_T * ROWF];   // 43,520 B
    int t = threadIdx.x;
    int BA = B * A;
    int r0 = blockIdx.x * PRE_T;

    // ---- cooperative coalesced tile load (base 16B-aligned: r0*340 % 16 == 0) ----
    int rows = BA - r0; if (rows > PRE_T) rows = PRE_T;
    int nf = rows * ROWF;
    const float* gbase = outputs + (size_t)r0 * ROWF;
    int n4 = nf >> 2;
    const float4* g4 = (const float4*)gbase;
    float4* l4 = (float4*)lds;
    for (int i = t; i < n4; i += PRE_T) l4[i] = g4[i];
    for (int i = (n4 << 2) + t; i < nf; i += PRE_T) lds[i] = gbase[i];
    __syncthreads();

    int idx = r0 + t;
    if (idx < A){
        float s = st[idx];
        xca[idx]  = (xs[idx] + 0.5f) * s;
        yca[idx]  = (ys[idx] + 0.5f) * s;
        rada[idx] = 2.5f * s;
    }
    if (idx >= BA || t >= rows) return;
    amg[idx] = 0; firstm[idx] = 0xFFFFFFFFu;

    int b = idx / A;
    int a = idx - b * A;
    const float* row = lds + t * ROWF;

    float ox = row[0], oy = row[1], ow = row[2], ohh = row[3], x4 = row[4];
    bbx[idx] = ox; bby[idx] = oy; bbw[idx] = ow; bbh[idx] = ohh;

    float so = sigmoidf_(x4);
    float s1 = 0.0f, b0 = 0.0f;
#pragma unroll 4
    for (int c = 0; c < C; c++){
        float xc = row[5 + c];
        if (useT) clsT[(size_t)c * BA + idx] = xc;   // coalesced store per c
        float p = sqrtf(sigmoidf_(xc) * so);
        s1 += fmaxf(log1pf(-p), -100.0f);
        b0 += fmaxf(xc, 0.0f) + log1pf(expf(-fabsf(xc)));
    }
    S1mp[idx] = s1; sobj[idx] = so; obj4[idx] = x4; bce0[idx] = b0;

    float xcv = (xs[a] + 0.5f) * st[a];
    float ycv = (ys[a] + 0.5f) * st[a];
    float rad = 2.5f * st[a];
    bool any = false;
    for (int m = 0; m < M && !any; m++){
        const float* lab = labels + ((size_t)b * M + m) * 5;
        float gx = lab[0], gy = lab[1], gw = lab[2], gh = lab[3], g4v = lab[4];
        if (!((gx + gy + gw + gh + g4v) > 0.0f)) continue;   // valid
        bool inb = (xcv > gx - 0.5f * gw) && (gx + 0.5f * gw > xcv) &&
                   (ycv > gy - 0.5f * gh) && (gy + 0.5f * gh > ycv);
        bool inc = (xcv > gx - rad) && (xcv < gx + rad) &&
                   (ycv > gy - rad) && (ycv < gy + rad);
        any = inb || inc;
    }
    fgbuf[idx] = any ? 1 : 0;
}

// ---------------- kernel 2: per-GT SimOTA assignment ----------------
// One block per (b, m). Fused single pass builds per-thread top-10 iou list and
// bottom-10 (cost, idx) list in registers; tournament extraction with 1
// barrier/round. Selections published via scattered atomics (no contention).
__global__ __launch_bounds__(TPB) void assign_kernel(
    const float* __restrict__ outputs,
    const float* __restrict__ xca, const float* __restrict__ yca,
    const float* __restrict__ rada,
    const float* __restrict__ labels, const float* __restrict__ S1mp,
    const float* __restrict__ sobj,
    const float* __restrict__ bbx, const float* __restrict__ bby,
    const float* __restrict__ bbw, const float* __restrict__ bbh,
    const unsigned char* __restrict__ fgbuf,
    const float* __restrict__ clsT, int useT,
    int* __restrict__ amg, unsigned int* __restrict__ firstm,
    int A, int M, int C, int B)
{
    int b = blockIdx.x / M;
    int m = blockIdx.x - b * M;
    int t = threadIdx.x;
    int lane = t & 63, wid = t >> 6;
    int BA = B * A;

    const float* lab = labels + ((size_t)b * M + m) * 5;
    float gx = lab[0], gy = lab[1], gw = lab[2], gh = lab[3], g4 = lab[4];
    int  gc = (int)g4;
    bool valid = (gx + gy + gw + gh + g4) > 0.0f;
    if (!valid) return;   // uniform for whole block

    const size_t base = (size_t)b * A;
    const float* outb = outputs + base * (C + 5);
    const unsigned char* fgb = fgbuf + base;
    const float* clscol = useT ? (clsT + (size_t)gc * BA + base) : nullptr;

    // per-thread lists (statically indexed -> registers)
    float tv[10];                 // top-10 ious, descending
    float cv[10]; int ci[10];     // bottom-10 costs (value, anchor), ascending
#pragma unroll
    for (int j = 0; j < 10; j++){ tv[j] = -2.0f; cv[j] = 4e9f; ci[j] = 0x7fffffff; }

    // ---- fused pass: masked iou + full cost per anchor ----
    for (int a = t; a < A; a += TPB){
        float x0 = bbx[base + a], y0 = bby[base + a];
        float w0 = bbw[base + a], h0 = bbh[base + a];
        bool fgflag = fgb[a] != 0;

        float v = 0.0f;
        if (fgflag) v = iou_fn(gx, gy, gw, gh, x0, y0, w0, h0);
        if (v > tv[9]){
            tv[9] = v;
#pragma unroll
            for (int j = 9; j > 0; j--){
                if (tv[j] > tv[j-1]){ float tm = tv[j]; tv[j] = tv[j-1]; tv[j-1] = tm; }
            }
        }

        float clsv = useT ? clscol[a] : outb[(size_t)a * (C + 5) + 5 + gc];
        float c = cost_eval(x0, y0, w0, h0, clsv,
                            sobj[base + a], S1mp[base + a],
                            xca[a], yca[a], rada[a], gx, gy, gw, gh, true, fgflag);
        if (c < cv[9] || (c == cv[9] && a < ci[9])){
            cv[9] = c; ci[9] = a;
#pragma unroll
            for (int j = 9; j > 0; j--){
                if (cv[j] < cv[j-1] || (cv[j] == cv[j-1] && ci[j] < ci[j-1])){
                    float tf = cv[j]; cv[j] = cv[j-1]; cv[j-1] = tf;
                    int  ti = ci[j]; ci[j] = ci[j-1]; ci[j-1] = ti;
                }
            }
        }
    }

    __shared__ float swv[2][4];
    __shared__ int   swi[2][4];

    // ---- top-10 iou sum, descending extraction (== lax.top_k order) ----
    float topsum = 0.0f;
    for (int k = 0; k < 10; k++){
        float v = tv[0];
        int who = t;
#pragma unroll
        for (int off = 32; off; off >>= 1){
            float v2 = __shfl_xor(v, off);
            int   w2 = __shfl_xor(who, off);
            if (v2 > v || (v2 == v && w2 < who)){ v = v2; who = w2; }
        }
        int slot = k & 1;
        if (lane == 0){ swv[slot][wid] = v; swi[slot][wid] = who; }
        __syncthreads();
        float gv = swv[slot][0]; int gwho = swi[slot][0];
#pragma unroll
        for (int w = 1; w < 4; w++){
            float v2 = swv[slot][w]; int w2 = swi[slot][w];
            if (v2 > gv || (v2 == gv && w2 < gwho)){ gv = v2; gwho = w2; }
        }
        topsum += gv;
        if (t == gwho){
#pragma unroll
            for (int j = 0; j < 9; j++) tv[j] = tv[j+1];
            tv[9] = -2.0f;
        }
    }
    int dyn_k = (int)topsum;            // trunc toward zero; 0 <= topsum <= 10
    if (dyn_k < 1) dyn_k = 1;
    if (dyn_k > 10) dyn_k = 10;

    __syncthreads();

    // ---- select dyn_k smallest costs, stable (value, index) order ----
    for (int k = 0; k < dyn_k; k++){
        float v = cv[0]; int ai = ci[0];
#pragma unroll
        for (int off = 32; off; off >>= 1){
            float v2 = __shfl_xor(v, off);
            int   a2 = __shfl_xor(ai, off);
            if (v2 < v || (v2 == v && a2 < ai)){ v = v2; ai = a2; }
        }
        int slot = k & 1;
        if (lane == 0){ swv[slot][wid] = v; swi[slot][wid] = ai; }
        __syncthreads();
        float gv = swv[slot][0]; int gai = swi[slot][0];
#pragma unroll
        for (int w = 1; w < 4; w++){
            float v2 = swv[slot][w]; int a2 = swi[slot][w];
            if (v2 < gv || (v2 == gv && a2 < gai)){ gv = v2; gai = a2; }
        }
        if (gv >= 1e8f) break;          // only BIG left (masked by fg&valid)
        if (cv[0] == gv && ci[0] == gai){   // unique winner thread
            atomicAdd(&amg[base + gai], 1);
            atomicMin(&firstm[base + gai], (unsigned)m);
#pragma unroll
            for (int j = 0; j < 9; j++){ cv[j] = cv[j+1]; ci[j] = ci[j+1]; }
            cv[9] = 4e9f; ci[9] = 0x7fffffff;
        }
    }
}

// ---------------- kernel 3: conflict resolution + loss (block partials) ----------------
__global__ __launch_bounds__(TPB) void finalize_kernel(
    const float* __restrict__ outputs,
    const float* __restrict__ xca, const float* __restrict__ yca,
    const float* __restrict__ rada,
    const float* __restrict__ labels, const float* __restrict__ S1mp,
    const float* __restrict__ sobj, const float* __restrict__ obj4,
    const float* __restrict__ bce0,
    const float* __restrict__ bbx, const float* __restrict__ bby,
    const float* __restrict__ bbw, const float* __restrict__ bbh,
    const unsigned char* __restrict__ fgbuf,
    const float* __restrict__ clsT, int useT,
    const int* __restrict__ amg, const unsigned int* __restrict__ firstm,
    float* __restrict__ pacc, int A, int M, int C, int B)
{
    int idx = blockIdx.x * TPB + threadIdx.x;
    int BA = B * A;
    float s_iou = 0.0f, s_obj = 0.0f, s_cls = 0.0f, s_nfg = 0.0f;
    if (idx < BA){
        int b = idx / A;
        int a = idx - b * A;
        int cnt = amg[idx];
        bool fgf = cnt >= 1;
        s_obj = bce_(obj4[idx], fgf ? 1.0f : 0.0f);
        if (fgf){
            float x0 = bbx[idx], y0 = bby[idx], w0 = bbw[idx], h0 = bbh[idx];
            int mgt = (int)firstm[idx];
            if (cnt > 1){
                // jnp.argmin(cost[:, a]) — first minimum; identical cost fn
                float S1 = S1mp[idx], so = sobj[idx];
                const float* orow = outputs + (size_t)idx * (C + 5);
                float best = 1e30f; int bi = 0;
                for (int m = 0; m < M; m++){
                    const float* lab = labels + ((size_t)b * M + m) * 5;
                    float gx = lab[0], gy = lab[1], gw = lab[2], gh = lab[3], g4 = lab[4];
                    bool valid = (gx + gy + gw + gh + g4) > 0.0f;
                    int gci = (int)g4;
                    float clsv = useT ? clsT[(size_t)gci * BA + idx] : orow[5 + gci];
                    float c = cost_eval(x0, y0, w0, h0, clsv, so, S1,
                                        xca[a], yca[a], rada[a],
                                        gx, gy, gw, gh, valid, true);
                    if (c < best){ best = c; bi = m; }
                }
                mgt = bi;
            }
            const float* lab = labels + ((size_t)b * M + mgt) * 5;
            float pious = iou_fn(lab[0], lab[1], lab[2], lab[3], x0, y0, w0, h0);
            s_iou = 1.0f - pious * pious;
            s_nfg = 1.0f;
            int gc = (int)lab[4];
            // sum_c bce(x_c, pious*onehot) = sum_c bce(x_c,0) - x_gc*pious
            float xgc = useT ? clsT[(size_t)gc * BA + idx]
                             : outputs[(size_t)idx * (C + 5) + 5 + gc];
            s_cls = bce0[idx] - xgc * pious;
        }
    }
    // wave64 shuffle reduction -> LDS -> one 4-float partial per block (NO atomics)
    for (int off = 32; off > 0; off >>= 1){
        s_iou += __shfl_down(s_iou, off);
        s_obj += __shfl_down(s_obj, off);
        s_cls += __shfl_down(s_cls, off);
        s_nfg += __shfl_down(s_nfg, off);
    }
    __shared__ float red[4][4];   // [wave][scalar]
    int lane = threadIdx.x & 63, wid = threadIdx.x >> 6;
    if (lane == 0){
        red[wid][0] = s_iou; red[wid][1] = s_obj;
        red[wid][2] = s_cls; red[wid][3] = s_nfg;
    }
    __syncthreads();
    if (threadIdx.x < 4){
        float v = red[0][threadIdx.x] + red[1][threadIdx.x]
                + red[2][threadIdx.x] + red[3][threadIdx.x];
        pacc[(size_t)blockIdx.x * 4 + threadIdx.x] = v;
    }
}

// ---------------- kernel 4: reduce block partials -> final loss ----------------
__global__ __launch_bounds__(TPB) void combine_kernel(
    const float* __restrict__ pacc, int nblk, float* __restrict__ out)
{
    float s0 = 0.0f, s1 = 0.0f, s2 = 0.0f, s3 = 0.0f;
    for (int i = threadIdx.x; i < nblk; i += TPB){
        s0 += pacc[(size_t)i * 4 + 0];
        s1 += pacc[(size_t)i * 4 + 1];
        s2 += pacc[(size_t)i * 4 + 2];
        s3 += pacc[(size_t)i * 4 + 3];
    }
    for (int off = 32; off > 0; off >>= 1){
        s0 += __shfl_down(s0, off);
        s1 += __shfl_down(s1, off);
        s2 += __shfl_down(s2, off);
        s3 += __shfl_down(s3, off);
    }
    __shared__ float red[4][4];
    int lane = threadIdx.x & 63, wid = threadIdx.x >> 6;
    if (lane == 0){ red[wid][0] = s0; red[wid][1] = s1; red[wid][2] = s2; red[wid][3] = s3; }
    __syncthreads();
    if (threadIdx.x == 0){
        float t0 = red[0][0] + red[1][0] + red[2][0] + red[3][0];
        float t1 = red[0][1] + red[1][1] + red[2][1] + red[3][1];
        float t2 = red[0][2] + red[1][2] + red[2][2] + red[3][2];
        float t3 = red[0][3] + red[1][3] + red[2][3] + red[3][3];
        float nfg = fmaxf(t3, 1.0f);
        out[0] = (5.0f * t0 + t1 + t2) / nfg;
    }
}

extern "C" void kernel_launch(void* const* d_in, const int* in_sizes, int n_in,
                              void* d_out, int out_size, void* d_ws, size_t ws_size,
                              hipStream_t stream)
{
    const float* outputs = (const float*)d_in[0];
    const float* xs      = (const float*)d_in[1];
    const float* ys      = (const float*)d_in[2];
    const float* st      = (const float*)d_in[3];
    const float* labels  = (const float*)d_in[4];

    const int C = 80;                       // fixed benchmark
    int A = in_sizes[1];
    int B = in_sizes[0] / (A * (C + 5));
    int M = in_sizes[4] / (B * 5);
    int BA = B * A;
    int nb  = (BA + TPB - 1) / TPB;
    int nbp = (BA + PRE_T - 1) / PRE_T;

    // workspace carve-up (256B aligned)
    char* w = (char*)d_ws;
    char* wend = (char*)d_ws + ws_size;
    auto carve = [&](size_t bytes) -> char* {
        char* p = w;
        w += (bytes + 255) & ~(size_t)255;
        return p;
    };
    float* S1mp = (float*)carve((size_t)BA * 4);
    float* sobj = (float*)carve((size_t)BA * 4);
    float* obj4 = (float*)carve((size_t)BA * 4);
    float* bce0 = (float*)carve((size_t)BA * 4);
    float* bbx  = (float*)carve((size_t)BA * 4);
    float* bby  = (float*)carve((size_t)BA * 4);
    float* bbw  = (float*)carve((size_t)BA * 4);
    float* bbh  = (float*)carve((size_t)BA * 4);
    int*   amg  = (int*)carve((size_t)BA * 4);
    unsigned int* firstm = (unsigned int*)carve((size_t)BA * 4);
    unsigned char* fgbuf = (unsigned char*)carve((size_t)BA);
    float* xca  = (float*)carve((size_t)A * 4);
    float* yca  = (float*)carve((size_t)A * 4);
    float* rada = (float*)carve((size_t)A * 4);
    float* pacc = (float*)carve((size_t)nb * 4 * 4);
    // class-logit transpose LAST: use only if workspace allows (~86 MB extra)
    char* clsT_p = w;
    size_t clsT_bytes = (size_t)C * BA * 4;
    int useT = (clsT_p + clsT_bytes <= wend) ? 1 : 0;
    float* clsT = useT ? (float*)clsT_p : nullptr;

    precompute_kernel<<<dim3(nbp), dim3(PRE_T), 0, stream>>>(
        outputs, xs, ys, st, labels, S1mp, sobj, obj4, bce0,
        bbx, bby, bbw, bbh, fgbuf, amg, firstm, xca, yca, rada,
        clsT, useT, A, M, C, B);
    assign_kernel<<<dim3(B * M), dim3(TPB), 0, stream>>>(
        outputs, xca, yca, rada, labels, S1mp, sobj, bbx, bby, bbw, bbh,
        fgbuf, clsT, useT, amg, firstm, A, M, C, B);
    finalize_kernel<<<dim3(nb), dim3(TPB), 0, stream>>>(
        outputs, xca, yca, rada, labels, S1mp, sobj, obj4, bce0,
        bbx, bby, bbw, bbh, fgbuf, clsT, useT, amg, firstm, pacc, A, M, C, B);
    combine_kernel<<<dim3(1), dim3(TPB), 0, stream>>>(pacc, nb, (float*)d_out);
}

// Round 5
// 367.254 us; speedup vs baseline: 1.6841x; 1.6841x over previous
//
#include <hip/hip_runtime.h>
#include <math.h>

#define TPB 256

__device__ __forceinline__ float sigmoidf_(float x){
    return 1.0f / (1.0f + expf(-x));
}

__device__ __forceinline__ float bce_(float x, float t){
    // max(x,0) - x*t + log1p(exp(-|x|))
    return fmaxf(x, 0.0f) - x * t + log1pf(expf(-fabsf(x)));
}

// IoU between box a (cx,cy,w,h) and box b (cx,cy,w,h) — mirrors _pairwise_iou.
__device__ float iou_fn(float ax, float ay, float aw, float ah,
                        float bx, float by, float bw, float bh){
#pragma clang fp contract(off)
    float tlx = fmaxf(ax - aw * 0.5f, bx - bw * 0.5f);
    float tly = fmaxf(ay - ah * 0.5f, by - bh * 0.5f);
    float brx = fminf(ax + aw * 0.5f, bx + bw * 0.5f);
    float bry = fminf(ay + ah * 0.5f, by + bh * 0.5f);
    float area_a = aw * ah;
    float area_b = bw * bh;
    bool  en = (tlx < brx) && (tly < bry);
    float area_i = en ? (brx - tlx) * (bry - tly) : 0.0f;
    return area_i / (area_a + area_b - area_i + 1e-16f);
}

// Full cost(m, a). MUST be bitwise-identical between assign (selection) and
// finalize (argmin conflict resolution) — hence contract(off) and shared code.
__device__ float cost_eval(float ox, float oy, float ow, float oh,
                           float clslogit, float so, float S1,
                           float xcv, float ycv, float rad,
                           float gx, float gy, float gw, float gh,
                           bool valid, bool fgflag){
#pragma clang fp contract(off)
    if (!(valid && fgflag)) return 1e9f;   // BIG
    float raw = iou_fn(gx, gy, gw, gh, ox, oy, ow, oh);
    bool inb = (xcv > gx - 0.5f * gw) && (gx + 0.5f * gw > xcv) &&
               (ycv > gy - 0.5f * gh) && (gy + 0.5f * gh > ycv);
    bool inc = (xcv > gx - rad) && (xcv < gx + rad) &&
               (ycv > gy - rad) && (ycv < gy + rad);
    bool in_both = inb && inc;
    float pt = sqrtf(sigmoidf_(clslogit) * so);
    float logp = fmaxf(logf(pt), -100.0f);
    float l1mp = fmaxf(log1pf(-pt), -100.0f);
    float cls_cost = -(logp + S1 - l1mp);
    return cls_cost + 3.0f * (-logf(raw + 1e-8f)) + (in_both ? 0.0f : 100000.0f);
}

// ---------------- kernel 1: per-anchor precompute (b-uniform blocks) ----------------
__global__ __launch_bounds__(TPB) void precompute_kernel(
    const float* __restrict__ outputs, const float* __restrict__ xs,
    const float* __restrict__ ys, const float* __restrict__ st,
    const float* __restrict__ labels,
    float* __restrict__ S1mp, float* __restrict__ sobj, float* __restrict__ obj4,
    float* __restrict__ bce0, float4* __restrict__ bb4,
    unsigned char* __restrict__ fgbuf,
    int* __restrict__ amg, unsigned int* __restrict__ firstm,
    float4* __restrict__ anc4,
    int A, int M, int C, int B, int nbA)
{
    __shared__ float slab[64 * 5];
    int t = threadIdx.x;
    int b = blockIdx.x / nbA;
    int chunk = blockIdx.x - b * nbA;
    int Ms = M < 64 ? M : 64;
    for (int i = t; i < Ms * 5; i += TPB) slab[i] = labels[(size_t)b * M * 5 + i];
    __syncthreads();

    int a = chunk * TPB + t;
    if (a >= A) return;
    size_t idx = (size_t)b * A + a;

    float s = st[a];
    float xcv = (xs[a] + 0.5f) * s;
    float ycv = (ys[a] + 0.5f) * s;
    float rad = 2.5f * s;
    if (b == 0) anc4[a] = make_float4(xcv, ycv, rad, 0.0f);

    amg[idx] = 0; firstm[idx] = 0xFFFFFFFFu;

    const float* o = outputs + idx * (size_t)(C + 5);
    float ox = o[0], oy = o[1], ow = o[2], ohh = o[3], x4 = o[4];
    bb4[idx] = make_float4(ox, oy, ow, ohh);

    float so = 1.0f / (1.0f + expf(-x4));    // bitwise == sigmoidf_(x4)
    float s1 = 0.0f, b0 = 0.0f;
#pragma unroll 4
    for (int c = 0; c < C; c++){
        float xc = o[5 + c];
        float u = expf(-xc);
        float sig = 1.0f / (1.0f + u);       // bitwise == sigmoidf_(xc)
        float p = sqrtf(sig * so);
        s1 += fmaxf(log1pf(-p), -100.0f);    // exact — feeds cost ranking
        // bce(xc,0) = log(1+e^xc) = -log(1-sigmoid(xc)); continuous-only path
        float om = 1.0f - sig;
        b0 += (om > 0.0f) ? -logf(om) : xc;
    }
    S1mp[idx] = s1; sobj[idx] = so; obj4[idx] = x4; bce0[idx] = b0;

    bool any = false;
    for (int m = 0; m < M && !any; m++){
        const float* lab = (m < Ms) ? (slab + m * 5)
                                    : (labels + ((size_t)b * M + m) * 5);
        float gx = lab[0], gy = lab[1], gw = lab[2], gh = lab[3], g4v = lab[4];
        if (!((gx + gy + gw + gh + g4v) > 0.0f)) continue;   // valid
        bool inb = (xcv > gx - 0.5f * gw) && (gx + 0.5f * gw > xcv) &&
                   (ycv > gy - 0.5f * gh) && (gy + 0.5f * gh > ycv);
        bool inc = (xcv > gx - rad) && (xcv < gx + rad) &&
                   (ycv > gy - rad) && (ycv < gy + rad);
        any = inb || inc;
    }
    fgbuf[idx] = any ? 1 : 0;
}

// ---------------- kernel 2: per-GT SimOTA assignment with in_both prefilter ----
// Provable bound: cost(in_both) <= ~8156 < 99900 <= cost(not in_both), so the
// dyn_k smallest costs are all in_both anchors whenever #in_both >= dyn_k.
// Full cost_eval runs only for in_both anchors (~tens per GT); rare
// block-uniform fallback rescans everything when dyn_k > #in_both.
__global__ __launch_bounds__(TPB) void assign_kernel(
    const float* __restrict__ outputs,
    const float4* __restrict__ anc4,
    const float* __restrict__ labels, const float* __restrict__ S1mp,
    const float* __restrict__ sobj, const float4* __restrict__ bb4,
    const unsigned char* __restrict__ fgbuf,
    int* __restrict__ amg, unsigned int* __restrict__ firstm,
    int A, int M, int C, int B)
{
    int b = blockIdx.x / M;
    int m = blockIdx.x - b * M;
    int t = threadIdx.x;
    int lane = t & 63, wid = t >> 6;

    const float* lab = labels + ((size_t)b * M + m) * 5;
    float gx = lab[0], gy = lab[1], gw = lab[2], gh = lab[3], g4 = lab[4];
    int  gc = (int)g4;
    bool valid = (gx + gy + gw + gh + g4) > 0.0f;
    if (!valid) return;   // uniform for whole block

    const size_t base = (size_t)b * A;
    const float* outb = outputs + base * (size_t)(C + 5);
    const unsigned char* fgb = fgbuf + base;

    float gl = gx - 0.5f * gw, gr = gx + 0.5f * gw;
    float gt_ = gy - 0.5f * gh, gb_ = gy + 0.5f * gh;

    // per-thread lists (statically indexed -> registers)
    float tv[10];                 // top-10 ious, descending
    float cv[10]; int ci[10];     // bottom-10 costs (value, anchor), ascending
#pragma unroll
    for (int j = 0; j < 10; j++){ tv[j] = -2.0f; cv[j] = 4e9f; ci[j] = 0x7fffffff; }
    int nib = 0;

    // ---- fused pass: iou for fg anchors (topk) + cost for in_both only ----
    for (int a = t; a < A; a += TPB){
        float4 bb = bb4[base + a];
        bool fgflag = fgb[a] != 0;

        float v = 0.0f;
        if (fgflag) v = iou_fn(gx, gy, gw, gh, bb.x, bb.y, bb.z, bb.w);
        if (v > tv[9]){
            tv[9] = v;
#pragma unroll
            for (int j = 9; j > 0; j--){
                if (tv[j] > tv[j-1]){ float tm = tv[j]; tv[j] = tv[j-1]; tv[j-1] = tm; }
            }
        }

        float4 an = anc4[a];
        bool inb = (an.x > gl) && (gr > an.x) && (an.y > gt_) && (gb_ > an.y);
        bool inc = (an.x > gx - an.z) && (an.x < gx + an.z) &&
                   (an.y > gy - an.z) && (an.y < gy + an.z);
        if (inb && inc){                       // in_both => in_boxes => fg
            nib++;
            float c = cost_eval(bb.x, bb.y, bb.z, bb.w,
                                outb[(size_t)a * (C + 5) + 5 + gc],
                                sobj[base + a], S1mp[base + a],
                                an.x, an.y, an.z, gx, gy, gw, gh, true, fgflag);
            if (c < cv[9] || (c == cv[9] && a < ci[9])){
                cv[9] = c; ci[9] = a;
#pragma unroll
                for (int j = 9; j > 0; j--){
                    if (cv[j] < cv[j-1] || (cv[j] == cv[j-1] && ci[j] < ci[j-1])){
                        float tf = cv[j]; cv[j] = cv[j-1]; cv[j-1] = tf;
                        int  ti = ci[j]; ci[j] = ci[j-1]; ci[j-1] = ti;
                    }
                }
            }
        }
    }

    // ---- block-total #in_both ----
    __shared__ int snib[4];
    int nr = nib;
#pragma unroll
    for (int off = 32; off; off >>= 1) nr += __shfl_xor(nr, off);
    if (lane == 0) snib[wid] = nr;
    __syncthreads();
    int total_nib = snib[0] + snib[1] + snib[2] + snib[3];

    __shared__ float swv[2][4];
    __shared__ int   swi[2][4];

    // ---- top-10 iou sum, descending extraction (== lax.top_k order) ----
    float topsum = 0.0f;
    for (int k = 0; k < 10; k++){
        float v = tv[0];
        int who = t;
#pragma unroll
        for (int off = 32; off; off >>= 1){
            float v2 = __shfl_xor(v, off);
            int   w2 = __shfl_xor(who, off);
            if (v2 > v || (v2 == v && w2 < who)){ v = v2; who = w2; }
        }
        int slot = k & 1;
        if (lane == 0){ swv[slot][wid] = v; swi[slot][wid] = who; }
        __syncthreads();
        float gv = swv[slot][0]; int gwho = swi[slot][0];
#pragma unroll
        for (int w = 1; w < 4; w++){
            float v2 = swv[slot][w]; int w2 = swi[slot][w];
            if (v2 > gv || (v2 == gv && w2 < gwho)){ gv = v2; gwho = w2; }
        }
        topsum += gv;
        if (t == gwho){
#pragma unroll
            for (int j = 0; j < 9; j++) tv[j] = tv[j+1];
            tv[9] = -2.0f;
        }
    }
    int dyn_k = (int)topsum;            // trunc toward zero; 0 <= topsum <= 10
    if (dyn_k < 1) dyn_k = 1;
    if (dyn_k > 10) dyn_k = 10;

    // ---- rare fallback: not enough in_both anchors -> full cost rescan ----
    if (dyn_k > total_nib){             // block-uniform condition
#pragma unroll
        for (int j = 0; j < 10; j++){ cv[j] = 4e9f; ci[j] = 0x7fffffff; }
        for (int a = t; a < A; a += TPB){
            float4 bb = bb4[base + a];
            bool fgflag = fgb[a] != 0;
            float4 an = anc4[a];
            float c = cost_eval(bb.x, bb.y, bb.z, bb.w,
                                outb[(size_t)a * (C + 5) + 5 + gc],
                                sobj[base + a], S1mp[base + a],
                                an.x, an.y, an.z, gx, gy, gw, gh, true, fgflag);
            if (c < cv[9] || (c == cv[9] && a < ci[9])){
                cv[9] = c; ci[9] = a;
#pragma unroll
                for (int j = 9; j > 0; j--){
                    if (cv[j] < cv[j-1] || (cv[j] == cv[j-1] && ci[j] < ci[j-1])){
                        float tf = cv[j]; cv[j] = cv[j-1]; cv[j-1] = tf;
                        int  ti = ci[j]; ci[j] = ci[j-1]; ci[j-1] = ti;
                    }
                }
            }
        }
    }
    __syncthreads();

    // ---- select dyn_k smallest costs, stable (value, index) order ----
    for (int k = 0; k < dyn_k; k++){
        float v = cv[0]; int ai = ci[0];
#pragma unroll
        for (int off = 32; off; off >>= 1){
            float v2 = __shfl_xor(v, off);
            int   a2 = __shfl_xor(ai, off);
            if (v2 < v || (v2 == v && a2 < ai)){ v = v2; ai = a2; }
        }
        int slot = k & 1;
        if (lane == 0){ swv[slot][wid] = v; swi[slot][wid] = ai; }
        __syncthreads();
        float gv = swv[slot][0]; int gai = swi[slot][0];
#pragma unroll
        for (int w = 1; w < 4; w++){
            float v2 = swv[slot][w]; int a2 = swi[slot][w];
            if (v2 < gv || (v2 == gv && a2 < gai)){ gv = v2; gai = a2; }
        }
        if (gv >= 1e8f) break;          // only BIG/1e5-masked left
        if (cv[0] == gv && ci[0] == gai){   // unique winner thread
            atomicAdd(&amg[base + gai], 1);
            atomicMin(&firstm[base + gai], (unsigned)m);
#pragma unroll
            for (int j = 0; j < 9; j++){ cv[j] = cv[j+1]; ci[j] = ci[j+1]; }
            cv[9] = 4e9f; ci[9] = 0x7fffffff;
        }
    }
}

// ---------------- kernel 3: conflict resolution + loss (block partials) ----------------
__global__ __launch_bounds__(TPB) void finalize_kernel(
    const float* __restrict__ outputs,
    const float4* __restrict__ anc4,
    const float* __restrict__ labels, const float* __restrict__ S1mp,
    const float* __restrict__ sobj, const float* __restrict__ obj4,
    const float* __restrict__ bce0, const float4* __restrict__ bb4,
    const unsigned char* __restrict__ fgbuf,
    const int* __restrict__ amg, const unsigned int* __restrict__ firstm,
    float* __restrict__ pacc, int A, int M, int C, int B)
{
    int idx = blockIdx.x * TPB + threadIdx.x;
    int BA = B * A;
    float s_iou = 0.0f, s_obj = 0.0f, s_cls = 0.0f, s_nfg = 0.0f;
    if (idx < BA){
        int b = idx / A;
        int a = idx - b * A;
        int cnt = amg[idx];
        bool fgf = cnt >= 1;
        s_obj = bce_(obj4[idx], fgf ? 1.0f : 0.0f);
        if (fgf){
            float4 bb = bb4[idx];
            int mgt = (int)firstm[idx];
            if (cnt > 1){
                // jnp.argmin(cost[:, a]) — first minimum; identical cost fn
                float S1 = S1mp[idx], so = sobj[idx];
                float4 an = anc4[a];
                const float* orow = outputs + (size_t)idx * (C + 5);
                float best = 1e30f; int bi = 0;
                for (int m = 0; m < M; m++){
                    const float* lab = labels + ((size_t)b * M + m) * 5;
                    float gx = lab[0], gy = lab[1], gw = lab[2], gh = lab[3], g4 = lab[4];
                    bool vld = (gx + gy + gw + gh + g4) > 0.0f;
                    float c = cost_eval(bb.x, bb.y, bb.z, bb.w, orow[5 + (int)g4],
                                        so, S1, an.x, an.y, an.z,
                                        gx, gy, gw, gh, vld, true);
                    if (c < best){ best = c; bi = m; }
                }
                mgt = bi;
            }
            const float* lab = labels + ((size_t)b * M + mgt) * 5;
            float pious = iou_fn(lab[0], lab[1], lab[2], lab[3], bb.x, bb.y, bb.z, bb.w);
            s_iou = 1.0f - pious * pious;
            s_nfg = 1.0f;
            int gc = (int)lab[4];
            // sum_c bce(x_c, pious*onehot) = sum_c bce(x_c,0) - x_gc*pious
            s_cls = bce0[idx] - outputs[(size_t)idx * (C + 5) + 5 + gc] * pious;
        }
    }
    // wave64 shuffle reduction -> LDS -> one 4-float partial per block (NO atomics)
    for (int off = 32; off > 0; off >>= 1){
        s_iou += __shfl_down(s_iou, off);
        s_obj += __shfl_down(s_obj, off);
        s_cls += __shfl_down(s_cls, off);
        s_nfg += __shfl_down(s_nfg, off);
    }
    __shared__ float red[4][4];   // [wave][scalar]
    int lane = threadIdx.x & 63, wid = threadIdx.x >> 6;
    if (lane == 0){
        red[wid][0] = s_iou; red[wid][1] = s_obj;
        red[wid][2] = s_cls; red[wid][3] = s_nfg;
    }
    __syncthreads();
    if (threadIdx.x < 4){
        float v = red[0][threadIdx.x] + red[1][threadIdx.x]
                + red[2][threadIdx.x] + red[3][threadIdx.x];
        pacc[(size_t)blockIdx.x * 4 + threadIdx.x] = v;
    }
}

// ---------------- kernel 4: reduce block partials -> final loss ----------------
__global__ __launch_bounds__(TPB) void combine_kernel(
    const float* __restrict__ pacc, int nblk, float* __restrict__ out)
{
    float s0 = 0.0f, s1 = 0.0f, s2 = 0.0f, s3 = 0.0f;
    for (int i = threadIdx.x; i < nblk; i += TPB){
        s0 += pacc[(size_t)i * 4 + 0];
        s1 += pacc[(size_t)i * 4 + 1];
        s2 += pacc[(size_t)i * 4 + 2];
        s3 += pacc[(size_t)i * 4 + 3];
    }
    for (int off = 32; off > 0; off >>= 1){
        s0 += __shfl_down(s0, off);
        s1 += __shfl_down(s1, off);
        s2 += __shfl_down(s2, off);
        s3 += __shfl_down(s3, off);
    }
    __shared__ float red[4][4];
    int lane = threadIdx.x & 63, wid = threadIdx.x >> 6;
    if (lane == 0){ red[wid][0] = s0; red[wid][1] = s1; red[wid][2] = s2; red[wid][3] = s3; }
    __syncthreads();
    if (threadIdx.x == 0){
        float t0 = red[0][0] + red[1][0] + red[2][0] + red[3][0];
        float t1 = red[0][1] + red[1][1] + red[2][1] + red[3][1];
        float t2 = red[0][2] + red[1][2] + red[2][2] + red[3][2];
        float t3 = red[0][3] + red[1][3] + red[2][3] + red[3][3];
        float nfg = fmaxf(t3, 1.0f);
        out[0] = (5.0f * t0 + t1 + t2) / nfg;
    }
}

extern "C" void kernel_launch(void* const* d_in, const int* in_sizes, int n_in,
                              void* d_out, int out_size, void* d_ws, size_t ws_size,
                              hipStream_t stream)
{
    const float* outputs = (const float*)d_in[0];
    const float* xs      = (const float*)d_in[1];
    const float* ys      = (const float*)d_in[2];
    const float* st      = (const float*)d_in[3];
    const float* labels  = (const float*)d_in[4];

    const int C = 80;                       // fixed benchmark
    int A = in_sizes[1];
    int B = in_sizes[0] / (A * (C + 5));
    int M = in_sizes[4] / (B * 5);
    int BA = B * A;
    int nb  = (BA + TPB - 1) / TPB;
    int nbA = (A + TPB - 1) / TPB;

    // workspace carve-up (256B aligned), ~12 MB total
    char* w = (char*)d_ws;
    auto carve = [&](size_t bytes) -> char* {
        char* p = w;
        w += (bytes + 255) & ~(size_t)255;
        return p;
    };
    float* S1mp = (float*)carve((size_t)BA * 4);
    float* sobj = (float*)carve((size_t)BA * 4);
    float* obj4 = (float*)carve((size_t)BA * 4);
    float* bce0 = (float*)carve((size_t)BA * 4);
    float4* bb4 = (float4*)carve((size_t)BA * 16);
    int*   amg  = (int*)carve((size_t)BA * 4);
    unsigned int* firstm = (unsigned int*)carve((size_t)BA * 4);
    unsigned char* fgbuf = (unsigned char*)carve((size_t)BA);
    float4* anc4 = (float4*)carve((size_t)A * 16);
    float* pacc = (float*)carve((size_t)nb * 4 * 4);

    precompute_kernel<<<dim3(B * nbA), dim3(TPB), 0, stream>>>(
        outputs, xs, ys, st, labels, S1mp, sobj, obj4, bce0,
        bb4, fgbuf, amg, firstm, anc4, A, M, C, B, nbA);
    assign_kernel<<<dim3(B * M), dim3(TPB), 0, stream>>>(
        outputs, anc4, labels, S1mp, sobj, bb4,
        fgbuf, amg, firstm, A, M, C, B);
    finalize_kernel<<<dim3(nb), dim3(TPB), 0, stream>>>(
        outputs, anc4, labels, S1mp, sobj, obj4, bce0,
        bb4, fgbuf, amg, firstm, pacc, A, M, C, B);
    combine_kernel<<<dim3(1), dim3(TPB), 0, stream>>>(pacc, nb, (float*)d_out);
}

// Round 6
// 344.422 us; speedup vs baseline: 1.7958x; 1.0663x over previous
//
#include <hip/hip_runtime.h>
#include <math.h>

#define TPB 256

#define LOG2E_F 1.4426950408889634f
#define LN2_F   0.6931471805599453f

__device__ __forceinline__ float sigmoidf_(float x){
    return 1.0f / (1.0f + expf(-x));
}

__device__ __forceinline__ float bce_(float x, float t){
    // max(x,0) - x*t + log1p(exp(-|x|))
    return fmaxf(x, 0.0f) - x * t + log1pf(expf(-fabsf(x)));
}

// IoU between box a (cx,cy,w,h) and box b (cx,cy,w,h) — mirrors _pairwise_iou.
__device__ float iou_fn(float ax, float ay, float aw, float ah,
                        float bx, float by, float bw, float bh){
#pragma clang fp contract(off)
    float tlx = fmaxf(ax - aw * 0.5f, bx - bw * 0.5f);
    float tly = fmaxf(ay - ah * 0.5f, by - bh * 0.5f);
    float brx = fminf(ax + aw * 0.5f, bx + bw * 0.5f);
    float bry = fminf(ay + ah * 0.5f, by + bh * 0.5f);
    float area_a = aw * ah;
    float area_b = bw * bh;
    bool  en = (tlx < brx) && (tly < bry);
    float area_i = en ? (brx - tlx) * (bry - tly) : 0.0f;
    return area_i / (area_a + area_b - area_i + 1e-16f);
}

// Full cost(m, a). MUST be bitwise-identical between assign (selection) and
// finalize (argmin conflict resolution) — hence contract(off) and shared code.
__device__ float cost_eval(float ox, float oy, float ow, float oh,
                           float clslogit, float so, float S1,
                           float xcv, float ycv, float rad,
                           float gx, float gy, float gw, float gh,
                           bool valid, bool fgflag){
#pragma clang fp contract(off)
    if (!(valid && fgflag)) return 1e9f;   // BIG
    float raw = iou_fn(gx, gy, gw, gh, ox, oy, ow, oh);
    bool inb = (xcv > gx - 0.5f * gw) && (gx + 0.5f * gw > xcv) &&
               (ycv > gy - 0.5f * gh) && (gy + 0.5f * gh > ycv);
    bool inc = (xcv > gx - rad) && (xcv < gx + rad) &&
               (ycv > gy - rad) && (ycv < gy + rad);
    bool in_both = inb && inc;
    float pt = sqrtf(sigmoidf_(clslogit) * so);
    float logp = fmaxf(logf(pt), -100.0f);
    float l1mp = fmaxf(log1pf(-pt), -100.0f);
    float cls_cost = -(logp + S1 - l1mp);
    return cls_cost + 3.0f * (-logf(raw + 1e-8f)) + (in_both ? 0.0f : 100000.0f);
}

// ---------------- kernel 1: per-anchor precompute (b-uniform blocks) ----------------
__global__ __launch_bounds__(TPB) void precompute_kernel(
    const float* __restrict__ outputs, const float* __restrict__ xs,
    const float* __restrict__ ys, const float* __restrict__ st,
    const float* __restrict__ labels,
    float* __restrict__ S1mp, float* __restrict__ sobj, float* __restrict__ obj4,
    float* __restrict__ bce0, float4* __restrict__ bb4,
    unsigned char* __restrict__ fgbuf,
    int* __restrict__ amg, unsigned int* __restrict__ firstm,
    float4* __restrict__ anc4,
    int A, int M, int C, int B, int nbA)
{
    __shared__ float slab[64 * 5];
    int t = threadIdx.x;
    int b = blockIdx.x / nbA;
    int chunk = blockIdx.x - b * nbA;
    int Ms = M < 64 ? M : 64;
    for (int i = t; i < Ms * 5; i += TPB) slab[i] = labels[(size_t)b * M * 5 + i];
    __syncthreads();

    int a = chunk * TPB + t;
    if (a >= A) return;
    size_t idx = (size_t)b * A + a;

    float s = st[a];
    float xcv = (xs[a] + 0.5f) * s;
    float ycv = (ys[a] + 0.5f) * s;
    float rad = 2.5f * s;
    if (b == 0) anc4[a] = make_float4(xcv, ycv, rad, 0.0f);

    amg[idx] = 0; firstm[idx] = 0xFFFFFFFFu;

    const float* o = outputs + idx * (size_t)(C + 5);
    float ox = o[0], oy = o[1], ow = o[2], ohh = o[3], x4 = o[4];
    bb4[idx] = make_float4(ox, oy, ow, ohh);

    // fast HW transcendentals: sigmoid = rcp(1+2^(-x*log2e)); ~1e-6 rel err,
    // only perturbs cost ranking by amounts far below selection margins.
    float so = __builtin_amdgcn_rcpf(1.0f + __builtin_amdgcn_exp2f(-x4 * LOG2E_F));
    float s1 = 0.0f, b0 = 0.0f;
#pragma unroll 4
    for (int c = 0; c < C; c++){
        float xc = o[5 + c];
        float u = __builtin_amdgcn_exp2f(-xc * LOG2E_F);
        float tden = 1.0f + u;
        float sig = __builtin_amdgcn_rcpf(tden);
        float p = __builtin_amdgcn_sqrtf(sig * so);
        // log1p(-p) ~= ln(1-p); if 1-p==0 -> -inf -> clamped to -100 (matches ref clamp)
        s1 += fmaxf(LN2_F * __builtin_amdgcn_logf(1.0f - p), -100.0f);
        // bce(xc,0) = ln(1+e^xc) = xc + ln(1+e^-xc)
        b0 += xc + LN2_F * __builtin_amdgcn_logf(tden);
    }
    S1mp[idx] = s1; sobj[idx] = so; obj4[idx] = x4; bce0[idx] = b0;

    bool any = false;
    for (int m = 0; m < M && !any; m++){
        const float* lab = (m < Ms) ? (slab + m * 5)
                                    : (labels + ((size_t)b * M + m) * 5);
        float gx = lab[0], gy = lab[1], gw = lab[2], gh = lab[3], g4v = lab[4];
        if (!((gx + gy + gw + gh + g4v) > 0.0f)) continue;   // valid
        bool inb = (xcv > gx - 0.5f * gw) && (gx + 0.5f * gw > xcv) &&
                   (ycv > gy - 0.5f * gh) && (gy + 0.5f * gh > ycv);
        bool inc = (xcv > gx - rad) && (xcv < gx + rad) &&
                   (ycv > gy - rad) && (ycv < gy + rad);
        any = inb || inc;
    }
    fgbuf[idx] = any ? 1 : 0;
}

// ---------------- kernel 1b: ordered fg compaction (1 block per image) ----------------
// Produces ascending-anchor-index compact arrays so compact order == original
// order (tie-breaks preserved). ballot/popc prefix sums, 3 barriers/chunk.
__global__ __launch_bounds__(TPB) void compact_kernel(
    const unsigned char* __restrict__ fgbuf, const float4* __restrict__ bb4,
    const float4* __restrict__ anc4, const float* __restrict__ S1mp,
    const float* __restrict__ sobj,
    float4* __restrict__ bbc, float4* __restrict__ ancc,
    float* __restrict__ sobc, int* __restrict__ aidxc, int* __restrict__ fgcnt,
    int A, int B)
{
    int b = blockIdx.x;
    int t = threadIdx.x;
    int lane = t & 63, wid = t >> 6;
    size_t base = (size_t)b * A;
    __shared__ int wtot[4];
    __shared__ int running;
    if (t == 0) running = 0;
    __syncthreads();
    for (int c0 = 0; c0 < A; c0 += TPB){
        int a = c0 + t;
        bool flag = (a < A) && (fgbuf[base + a] != 0);
        unsigned long long mask = __ballot(flag);
        int prefix = __popcll(mask & ((1ull << lane) - 1ull));
        int tot = __popcll(mask);
        if (lane == 0) wtot[wid] = tot;
        __syncthreads();
        int off = running;
        for (int w = 0; w < wid; w++) off += wtot[w];
        if (flag){
            int pos = off + prefix;
            bbc[base + pos] = bb4[base + a];
            float4 an = anc4[a];
            an.w = S1mp[base + a];
            ancc[base + pos] = an;
            sobc[base + pos] = sobj[base + a];
            aidxc[base + pos] = a;
        }
        __syncthreads();
        if (t == 0) running += wtot[0] + wtot[1] + wtot[2] + wtot[3];
        __syncthreads();
    }
    if (t == 0) fgcnt[b] = running;
}

// ---------------- kernel 2: per-GT SimOTA assignment over compacted fg set ----
// Non-fg anchors have iou==0 (pad topsum with zeros) and cost==BIG (never
// selected before break) -> scanning only the fg set is exactly equivalent.
// in_both prefilter as in R4: cost(in_both)<=~8156 < 99900<=cost(other fg).
__global__ __launch_bounds__(TPB) void assign_kernel(
    const float* __restrict__ outputs,
    const float* __restrict__ labels,
    const float4* __restrict__ bbc, const float4* __restrict__ ancc,
    const float* __restrict__ sobc, const int* __restrict__ aidxc,
    const int* __restrict__ fgcnt,
    int* __restrict__ amg, unsigned int* __restrict__ firstm,
    int A, int M, int C, int B)
{
    int b = blockIdx.x / M;
    int m = blockIdx.x - b * M;
    int t = threadIdx.x;
    int lane = t & 63, wid = t >> 6;

    const float* lab = labels + ((size_t)b * M + m) * 5;
    float gx = lab[0], gy = lab[1], gw = lab[2], gh = lab[3], g4 = lab[4];
    int  gc = (int)g4;
    bool valid = (gx + gy + gw + gh + g4) > 0.0f;
    if (!valid) return;   // uniform for whole block

    const size_t base = (size_t)b * A;
    const float* outb = outputs + base * (size_t)(C + 5);
    int n = fgcnt[b];

    float gl = gx - 0.5f * gw, gr = gx + 0.5f * gw;
    float gt_ = gy - 0.5f * gh, gb_ = gy + 0.5f * gh;

    // per-thread lists (statically indexed -> registers)
    float tv[10];                 // top-10 ious, descending
    float cv[10]; int ci[10];     // bottom-10 costs (value, orig anchor), ascending
#pragma unroll
    for (int j = 0; j < 10; j++){ tv[j] = -2.0f; cv[j] = 4e9f; ci[j] = 0x7fffffff; }
    int nib = 0;

    // ---- fused pass over fg set: iou (topk) + cost for in_both only ----
    for (int i = t; i < n; i += TPB){
        float4 bb = bbc[base + i];
        float4 an = ancc[base + i];     // x=xcv y=ycv z=rad w=S1

        float v = iou_fn(gx, gy, gw, gh, bb.x, bb.y, bb.z, bb.w);
        if (v > tv[9]){
            tv[9] = v;
#pragma unroll
            for (int j = 9; j > 0; j--){
                if (tv[j] > tv[j-1]){ float tm = tv[j]; tv[j] = tv[j-1]; tv[j-1] = tm; }
            }
        }

        bool inb = (an.x > gl) && (gr > an.x) && (an.y > gt_) && (gb_ > an.y);
        bool inc = (an.x > gx - an.z) && (an.x < gx + an.z) &&
                   (an.y > gy - an.z) && (an.y < gy + an.z);
        if (inb && inc){
            nib++;
            int a = aidxc[base + i];
            float c = cost_eval(bb.x, bb.y, bb.z, bb.w,
                                outb[(size_t)a * (C + 5) + 5 + gc],
                                sobc[base + i], an.w,
                                an.x, an.y, an.z, gx, gy, gw, gh, true, true);
            if (c < cv[9] || (c == cv[9] && a < ci[9])){
                cv[9] = c; ci[9] = a;
#pragma unroll
                for (int j = 9; j > 0; j--){
                    if (cv[j] < cv[j-1] || (cv[j] == cv[j-1] && ci[j] < ci[j-1])){
                        float tf = cv[j]; cv[j] = cv[j-1]; cv[j-1] = tf;
                        int  ti = ci[j]; ci[j] = ci[j-1]; ci[j-1] = ti;
                    }
                }
            }
        }
    }

    // ---- block-total #in_both ----
    __shared__ int snib[4];
    int nr = nib;
#pragma unroll
    for (int off = 32; off; off >>= 1) nr += __shfl_xor(nr, off);
    if (lane == 0) snib[wid] = nr;
    __syncthreads();
    int total_nib = snib[0] + snib[1] + snib[2] + snib[3];

    __shared__ float swv[2][4];
    __shared__ int   swi[2][4];

    // ---- top-10 iou sum, descending extraction (== lax.top_k order) ----
    // Clamp extracted value at 0: non-fg anchors contribute exact zeros in the
    // reference; our -2 sentinels stand in for them.
    float topsum = 0.0f;
    for (int k = 0; k < 10; k++){
        float v = tv[0];
        int who = t;
#pragma unroll
        for (int off = 32; off; off >>= 1){
            float v2 = __shfl_xor(v, off);
            int   w2 = __shfl_xor(who, off);
            if (v2 > v || (v2 == v && w2 < who)){ v = v2; who = w2; }
        }
        int slot = k & 1;
        if (lane == 0){ swv[slot][wid] = v; swi[slot][wid] = who; }
        __syncthreads();
        float gv = swv[slot][0]; int gwho = swi[slot][0];
#pragma unroll
        for (int w = 1; w < 4; w++){
            float v2 = swv[slot][w]; int w2 = swi[slot][w];
            if (v2 > gv || (v2 == gv && w2 < gwho)){ gv = v2; gwho = w2; }
        }
        topsum += fmaxf(gv, 0.0f);
        if (t == gwho){
#pragma unroll
            for (int j = 0; j < 9; j++) tv[j] = tv[j+1];
            tv[9] = -2.0f;
        }
    }
    int dyn_k = (int)topsum;            // trunc toward zero; 0 <= topsum <= 10
    if (dyn_k < 1) dyn_k = 1;
    if (dyn_k > 10) dyn_k = 10;

    // ---- rare fallback: not enough in_both anchors -> rescan all fg anchors ----
    if (dyn_k > total_nib){             // block-uniform condition
#pragma unroll
        for (int j = 0; j < 10; j++){ cv[j] = 4e9f; ci[j] = 0x7fffffff; }
        for (int i = t; i < n; i += TPB){
            float4 bb = bbc[base + i];
            float4 an = ancc[base + i];
            int a = aidxc[base + i];
            float c = cost_eval(bb.x, bb.y, bb.z, bb.w,
                                outb[(size_t)a * (C + 5) + 5 + gc],
                                sobc[base + i], an.w,
                                an.x, an.y, an.z, gx, gy, gw, gh, true, true);
            if (c < cv[9] || (c == cv[9] && a < ci[9])){
                cv[9] = c; ci[9] = a;
#pragma unroll
                for (int j = 9; j > 0; j--){
                    if (cv[j] < cv[j-1] || (cv[j] == cv[j-1] && ci[j] < ci[j-1])){
                        float tf = cv[j]; cv[j] = cv[j-1]; cv[j-1] = tf;
                        int  ti = ci[j]; ci[j] = ci[j-1]; ci[j-1] = ti;
                    }
                }
            }
        }
    }
    __syncthreads();

    // ---- select dyn_k smallest costs, stable (value, index) order ----
    for (int k = 0; k < dyn_k; k++){
        float v = cv[0]; int ai = ci[0];
#pragma unroll
        for (int off = 32; off; off >>= 1){
            float v2 = __shfl_xor(v, off);
            int   a2 = __shfl_xor(ai, off);
            if (v2 < v || (v2 == v && a2 < ai)){ v = v2; ai = a2; }
        }
        int slot = k & 1;
        if (lane == 0){ swv[slot][wid] = v; swi[slot][wid] = ai; }
        __syncthreads();
        float gv = swv[slot][0]; int gai = swi[slot][0];
#pragma unroll
        for (int w = 1; w < 4; w++){
            float v2 = swv[slot][w]; int a2 = swi[slot][w];
            if (v2 < gv || (v2 == gv && a2 < gai)){ gv = v2; gai = a2; }
        }
        if (gv >= 1e8f) break;          // only BIG left (fg set exhausted)
        if (cv[0] == gv && ci[0] == gai){   // unique winner thread
            atomicAdd(&amg[base + gai], 1);
            atomicMin(&firstm[base + gai], (unsigned)m);
#pragma unroll
            for (int j = 0; j < 9; j++){ cv[j] = cv[j+1]; ci[j] = ci[j+1]; }
            cv[9] = 4e9f; ci[9] = 0x7fffffff;
        }
    }
}

// ---------------- kernel 3: conflict resolution + loss (block partials) ----------------
__global__ __launch_bounds__(TPB) void finalize_kernel(
    const float* __restrict__ outputs,
    const float4* __restrict__ anc4,
    const float* __restrict__ labels, const float* __restrict__ S1mp,
    const float* __restrict__ sobj, const float* __restrict__ obj4,
    const float* __restrict__ bce0, const float4* __restrict__ bb4,
    const int* __restrict__ amg, const unsigned int* __restrict__ firstm,
    float* __restrict__ pacc, int A, int M, int C, int B)
{
    int idx = blockIdx.x * TPB + threadIdx.x;
    int BA = B * A;
    float s_iou = 0.0f, s_obj = 0.0f, s_cls = 0.0f, s_nfg = 0.0f;
    if (idx < BA){
        int b = idx / A;
        int a = idx - b * A;
        int cnt = amg[idx];
        bool fgf = cnt >= 1;
        s_obj = bce_(obj4[idx], fgf ? 1.0f : 0.0f);
        if (fgf){
            float4 bb = bb4[idx];
            int mgt = (int)firstm[idx];
            if (cnt > 1){
                // jnp.argmin(cost[:, a]) — first minimum; identical cost fn
                float S1 = S1mp[idx], so = sobj[idx];
                float4 an = anc4[a];
                const float* orow = outputs + (size_t)idx * (C + 5);
                float best = 1e30f; int bi = 0;
                for (int m = 0; m < M; m++){
                    const float* lab = labels + ((size_t)b * M + m) * 5;
                    float gx = lab[0], gy = lab[1], gw = lab[2], gh = lab[3], g4 = lab[4];
                    bool vld = (gx + gy + gw + gh + g4) > 0.0f;
                    float c = cost_eval(bb.x, bb.y, bb.z, bb.w, orow[5 + (int)g4],
                                        so, S1, an.x, an.y, an.z,
                                        gx, gy, gw, gh, vld, true);
                    if (c < best){ best = c; bi = m; }
                }
                mgt = bi;
            }
            const float* lab = labels + ((size_t)b * M + mgt) * 5;
            float pious = iou_fn(lab[0], lab[1], lab[2], lab[3], bb.x, bb.y, bb.z, bb.w);
            s_iou = 1.0f - pious * pious;
            s_nfg = 1.0f;
            int gc = (int)lab[4];
            // sum_c bce(x_c, pious*onehot) = sum_c bce(x_c,0) - x_gc*pious
            s_cls = bce0[idx] - outputs[(size_t)idx * (C + 5) + 5 + gc] * pious;
        }
    }
    // wave64 shuffle reduction -> LDS -> one 4-float partial per block (NO atomics)
    for (int off = 32; off > 0; off >>= 1){
        s_iou += __shfl_down(s_iou, off);
        s_obj += __shfl_down(s_obj, off);
        s_cls += __shfl_down(s_cls, off);
        s_nfg += __shfl_down(s_nfg, off);
    }
    __shared__ float red[4][4];   // [wave][scalar]
    int lane = threadIdx.x & 63, wid = threadIdx.x >> 6;
    if (lane == 0){
        red[wid][0] = s_iou; red[wid][1] = s_obj;
        red[wid][2] = s_cls; red[wid][3] = s_nfg;
    }
    __syncthreads();
    if (threadIdx.x < 4){
        float v = red[0][threadIdx.x] + red[1][threadIdx.x]
                + red[2][threadIdx.x] + red[3][threadIdx.x];
        pacc[(size_t)blockIdx.x * 4 + threadIdx.x] = v;
    }
}

// ---------------- kernel 4: reduce block partials -> final loss ----------------
__global__ __launch_bounds__(TPB) void combine_kernel(
    const float* __restrict__ pacc, int nblk, float* __restrict__ out)
{
    float s0 = 0.0f, s1 = 0.0f, s2 = 0.0f, s3 = 0.0f;
    for (int i = threadIdx.x; i < nblk; i += TPB){
        s0 += pacc[(size_t)i * 4 + 0];
        s1 += pacc[(size_t)i * 4 + 1];
        s2 += pacc[(size_t)i * 4 + 2];
        s3 += pacc[(size_t)i * 4 + 3];
    }
    for (int off = 32; off > 0; off >>= 1){
        s0 += __shfl_down(s0, off);
        s1 += __shfl_down(s1, off);
        s2 += __shfl_down(s2, off);
        s3 += __shfl_down(s3, off);
    }
    __shared__ float red[4][4];
    int lane = threadIdx.x & 63, wid = threadIdx.x >> 6;
    if (lane == 0){ red[wid][0] = s0; red[wid][1] = s1; red[wid][2] = s2; red[wid][3] = s3; }
    __syncthreads();
    if (threadIdx.x == 0){
        float t0 = red[0][0] + red[1][0] + red[2][0] + red[3][0];
        float t1 = red[0][1] + red[1][1] + red[2][1] + red[3][1];
        float t2 = red[0][2] + red[1][2] + red[2][2] + red[3][2];
        float t3 = red[0][3] + red[1][3] + red[2][3] + red[3][3];
        float nfg = fmaxf(t3, 1.0f);
        out[0] = (5.0f * t0 + t1 + t2) / nfg;
    }
}

extern "C" void kernel_launch(void* const* d_in, const int* in_sizes, int n_in,
                              void* d_out, int out_size, void* d_ws, size_t ws_size,
                              hipStream_t stream)
{
    const float* outputs = (const float*)d_in[0];
    const float* xs      = (const float*)d_in[1];
    const float* ys      = (const float*)d_in[2];
    const float* st      = (const float*)d_in[3];
    const float* labels  = (const float*)d_in[4];

    const int C = 80;                       // fixed benchmark
    int A = in_sizes[1];
    int B = in_sizes[0] / (A * (C + 5));
    int M = in_sizes[4] / (B * 5);
    int BA = B * A;
    int nb  = (BA + TPB - 1) / TPB;
    int nbA = (A + TPB - 1) / TPB;

    // workspace carve-up (256B aligned), ~23 MB total
    char* w = (char*)d_ws;
    auto carve = [&](size_t bytes) -> char* {
        char* p = w;
        w += (bytes + 255) & ~(size_t)255;
        return p;
    };
    float* S1mp = (float*)carve((size_t)BA * 4);
    float* sobj = (float*)carve((size_t)BA * 4);
    float* obj4 = (float*)carve((size_t)BA * 4);
    float* bce0 = (float*)carve((size_t)BA * 4);
    float4* bb4 = (float4*)carve((size_t)BA * 16);
    int*   amg  = (int*)carve((size_t)BA * 4);
    unsigned int* firstm = (unsigned int*)carve((size_t)BA * 4);
    unsigned char* fgbuf = (unsigned char*)carve((size_t)BA);
    float4* anc4 = (float4*)carve((size_t)A * 16);
    float* pacc = (float*)carve((size_t)nb * 4 * 4);
    // compacted fg arrays
    float4* bbc  = (float4*)carve((size_t)BA * 16);
    float4* ancc = (float4*)carve((size_t)BA * 16);
    float*  sobc = (float*)carve((size_t)BA * 4);
    int*    aidxc= (int*)carve((size_t)BA * 4);
    int*    fgcnt= (int*)carve((size_t)B * 4);

    precompute_kernel<<<dim3(B * nbA), dim3(TPB), 0, stream>>>(
        outputs, xs, ys, st, labels, S1mp, sobj, obj4, bce0,
        bb4, fgbuf, amg, firstm, anc4, A, M, C, B, nbA);
    compact_kernel<<<dim3(B), dim3(TPB), 0, stream>>>(
        fgbuf, bb4, anc4, S1mp, sobj, bbc, ancc, sobc, aidxc, fgcnt, A, B);
    assign_kernel<<<dim3(B * M), dim3(TPB), 0, stream>>>(
        outputs, labels, bbc, ancc, sobc, aidxc, fgcnt,
        amg, firstm, A, M, C, B);
    finalize_kernel<<<dim3(nb), dim3(TPB), 0, stream>>>(
        outputs, anc4, labels, S1mp, sobj, obj4, bce0,
        bb4, amg, firstm, pacc, A, M, C, B);
    combine_kernel<<<dim3(1), dim3(TPB), 0, stream>>>(pacc, nb, (float*)d_out);
}